// Round 1
// baseline (1272.559 us; speedup 1.0000x reference)
//
#include <hip/hip_runtime.h>
#include <hip/hip_bf16.h>

typedef unsigned short ushort_t;
typedef short short8_t __attribute__((ext_vector_type(8)));
typedef float f32x4 __attribute__((ext_vector_type(4)));

#define NBATCH 16
#define SEQ    60
#define NSTK   50
#define HID    128
#define G3     384      // 3*HID
#define NIMG   800      // B*N images
#define IH     64
#define IW     60
#define P1H    32
#define P1W    30
#define P2C    64
#define FCIN   15360

// ---- workspace layout (float offsets) ----
#define OFF_WIHT   0u           // 50*384            = 19200
#define OFF_WHHF   19200u       // 49152 ushort      = 24576 floats (bf16 MFMA-fragment-swizzled W_hh^T)
#define OFF_GI     43776u       // 60*16*384         = 368640
#define OFF_HLAST  412416u      // 16*128            = 2048
#define OFF_POOL2  414464u      // 800*15360         = 12288000
#define OFF_FC1P   12702464u    // 16*832*64         = 851968
#define OFF_FC2O   13554432u    // 800*128           = 102400
#define WS_FLOATS  13656832u    // ~54.6 MB

// ---------------- shared-memory layouts for the mega kernel ----------------
struct ConvS {
    float imgp[66][62];        // zero-padded input image        16368 B
    float pool1[32][32][30];   // conv1+relu+pool1 result       122880 B
    float w1[288];             // conv1 weights                   1152 B
    float b1[32];
};
struct GruS {
    float   h[2048];           // h[b][k] f32
    float   gh[6144];          // gh[b][j] f32
    ushort_t hb[2048];         // h in bf16 (MFMA A operand), 16B-aligned offset
    ushort_t wf[49152];        // W_hh^T bf16, MFMA-B-fragment order
};
#define SMEM_BYTES 140544      // >= max(sizeof(ConvS)=140528, sizeof(GruS)=135168)

// ---------------- small prep: transpose W_ih, swizzle W_hh to bf16 fragments ----
__global__ __launch_bounds__(256) void k_prep(const float* __restrict__ wih,
                                              const float* __restrict__ whh,
                                              float* __restrict__ wihT,
                                              ushort_t* __restrict__ whhf)
{
    const int idx = blockIdx.x * 256 + threadIdx.x;
    if (idx < 19200) {
        const int j = idx % G3, k = idx / G3;
        wihT[idx] = wih[j * NSTK + k];
    } else if (idx < 19200 + 49152) {
        const int e = idx - 19200;
        // e = (((jt*4+ks)*64 + l)*8 + i)
        const int i = e & 7, l = (e >> 3) & 63, ksj = e >> 9;
        const int ks = ksj & 3, jt = ksj >> 2;
        const int j = jt * 16 + (l & 15);                 // B col = lane&15
        const int k = ks * 32 + ((l >> 4) << 3) + i;      // B k   = (lane>>4)*8+i
        __hip_bfloat16 hv = __float2bfloat16(whh[j * HID + k]);
        whhf[e] = *(ushort_t*)&hv;
    }
}

// ---------------- GI[s][b][j] = b_ih[j] + x[b,s,:] . W_ih[j,:] ----------------
__global__ __launch_bounds__(384) void k_gi(const float* __restrict__ xnum,
                                            const float* __restrict__ wihT,
                                            const float* __restrict__ bih,
                                            float* __restrict__ GI)
{
    const int sb = blockIdx.x;
    const int s = sb >> 4, b = sb & 15;
    const int j = threadIdx.x;
    const float* xr = xnum + (size_t)(b * SEQ + s) * NSTK;
    float a = bih[j];
    for (int k = 0; k < NSTK; ++k) a = fmaf(xr[k], wihT[k * G3 + j], a);
    GI[((size_t)s * 16 + b) * G3 + j] = a;
}

// ---------------- mega kernel: block 0 = GRU, blocks 1..800 = one image each ----
__global__ __launch_bounds__(512) void k_mega(const float* __restrict__ x_img,
                                              const float* __restrict__ c1w,
                                              const float* __restrict__ c1b,
                                              const float* __restrict__ c2w,
                                              const float* __restrict__ c2b,
                                              const float* __restrict__ GI,
                                              const ushort_t* __restrict__ whhf,
                                              const float* __restrict__ bhh,
                                              float* __restrict__ pool2,
                                              float* __restrict__ hlast)
{
    extern __shared__ char smraw[];
    const int tid = threadIdx.x;
    const int bid = blockIdx.x;

    if (bid == 0) {
        // ================= GRU (bf16 MFMA for h @ W_hh^T) =================
        GruS* g = (GruS*)smraw;
        for (int i = tid; i < 24576; i += 512)
            ((unsigned int*)g->wf)[i] = ((const unsigned int*)whhf)[i];
        for (int i = tid; i < 2048; i += 512) { g->h[i] = 0.f; g->hb[i] = (ushort_t)0; }
        __syncthreads();
        const int w = tid >> 6, l = tid & 63;
        const int arow = l & 15, kq = l >> 4;  // A: row=lane&15, k-slice=(lane>>4)
        for (int s = 0; s < SEQ; ++s) {
            // gh[16][384] = h[16][128] @ WhhT[128][384] ; 8 waves x 3 j-tiles
            #pragma unroll
            for (int jj = 0; jj < 3; ++jj) {
                const int jt = w * 3 + jj;
                f32x4 a = {0.f, 0.f, 0.f, 0.f};
                #pragma unroll
                for (int ks = 0; ks < 4; ++ks) {
                    short8_t af = *(const short8_t*)&g->hb[arow * 128 + ks * 32 + kq * 8];
                    short8_t bf = *(const short8_t*)&g->wf[(((jt << 2) | ks) * 64 + l) * 8];
                    a = __builtin_amdgcn_mfma_f32_16x16x32_bf16(af, bf, a, 0, 0, 0);
                }
                #pragma unroll
                for (int r = 0; r < 4; ++r)                 // D: row=(lane>>4)*4+r, col=lane&15
                    g->gh[(kq * 4 + r) * G3 + jt * 16 + arow] = a[r];
            }
            __syncthreads();
            const float* gis = GI + (size_t)s * 16 * G3;
            #pragma unroll
            for (int q = 0; q < 4; ++q) {
                const int p = tid + q * 512;                // p = b*128 + hh
                const int b = p >> 7, hh = p & 127;
                const float gir = gis[b * G3 + hh];
                const float giz = gis[b * G3 + 128 + hh];
                const float gin = gis[b * G3 + 256 + hh];
                const float ghr = g->gh[b * G3 + hh]       + bhh[hh];
                const float ghz = g->gh[b * G3 + 128 + hh] + bhh[128 + hh];
                const float ghn = g->gh[b * G3 + 256 + hh] + bhh[256 + hh];
                const float rg = 1.f / (1.f + expf(-(gir + ghr)));
                const float zg = 1.f / (1.f + expf(-(giz + ghz)));
                const float ng = tanhf(gin + rg * ghn);
                const float hn = (1.f - zg) * ng + zg * g->h[p];
                g->h[p] = hn;
                __hip_bfloat16 hb16 = __float2bfloat16(hn);
                g->hb[p] = *(ushort_t*)&hb16;
            }
            __syncthreads();
        }
        for (int i = tid; i < 2048; i += 512) hlast[i] = g->h[i];
        return;
    }

    // ================= CNN: conv1+relu+pool1 (LDS) -> conv2+relu+pool2 (global) ====
    ConvS* c = (ConvS*)smraw;
    const int img = bid - 1;
    const float* xim = x_img + (size_t)img * (IH * IW);
    for (int i = tid; i < 66 * 62; i += 512) ((float*)c->imgp)[i] = 0.f;
    __syncthreads();
    for (int i = tid; i < IH * IW; i += 512) {
        const int y = i / IW, x = i - y * IW;
        c->imgp[y + 1][x + 1] = xim[i];
    }
    for (int i = tid; i < 288; i += 512) c->w1[i] = c1w[i];
    if (tid < 32) c->b1[tid] = c1b[tid];
    __syncthreads();

    // ---- conv1: each thread 60 pooled outputs ----
    for (int p = 0; p < 60; ++p) {
        const int o = tid + p * 512;
        const int ch = o / 960; const int r = o - ch * 960;
        const int py = r / P1W;  const int px = r - py * P1W;
        float wr[9];
        #pragma unroll
        for (int q = 0; q < 9; ++q) wr[q] = c->w1[ch * 9 + q];
        const float bia = c->b1[ch];
        float patch[4][4];
        #pragma unroll
        for (int yy = 0; yy < 4; ++yy)
            #pragma unroll
            for (int xx = 0; xx < 4; ++xx) patch[yy][xx] = c->imgp[2 * py + yy][2 * px + xx];
        float best = 0.f;   // relu(max(conv+b)) with best init 0 == max(relu(...))
        #pragma unroll
        for (int dy = 0; dy < 2; ++dy)
            #pragma unroll
            for (int dx = 0; dx < 2; ++dx) {
                float sv = 0.f;
                #pragma unroll
                for (int ky = 0; ky < 3; ++ky)
                    #pragma unroll
                    for (int kx = 0; kx < 3; ++kx)
                        sv = fmaf(patch[dy + ky][dx + kx], wr[ky * 3 + kx], sv);
                best = fmaxf(best, sv + bia);
            }
        c->pool1[ch][py][px] = best;
    }
    __syncthreads();

    // ---- conv2: thread = (pr, ocA) handles oc {ocA, ocA+32}, pooled row pr ----
    const int pr  = tid & 15;
    const int ocA = tid >> 4;
    const int ocB = ocA + 32;
    float acc[2][2][30];
    #pragma unroll
    for (int a0 = 0; a0 < 2; ++a0)
        #pragma unroll
        for (int a1 = 0; a1 < 2; ++a1)
            #pragma unroll
            for (int a2 = 0; a2 < 30; ++a2) acc[a0][a1][a2] = 0.f;

    for (int ic = 0; ic < 32; ++ic) {
        float wA[9], wB[9];
        const float* gwa = c2w + ((size_t)ocA * 32 + ic) * 9;
        const float* gwb = c2w + ((size_t)ocB * 32 + ic) * 9;
        #pragma unroll
        for (int q = 0; q < 9; ++q) { wA[q] = gwa[q]; wB[q] = gwb[q]; }
        #pragma unroll
        for (int rr = 0; rr < 4; ++rr) {          // input rows 2pr-1 .. 2pr+2
            const int ir = pr * 2 - 1 + rr;       // conv row0 ky = rr, row1 ky = rr-1
            if (ir >= 0 && ir < P1H) {
                const float* row = &c->pool1[ic][ir][0];
                float x0 = 0.f, x1 = row[0];
                #pragma unroll
                for (int cx = 0; cx < 30; ++cx) {
                    const float x2 = (cx < 29) ? row[cx + 1] : 0.f;
                    if (rr < 3) {
                        acc[0][0][cx] = fmaf(wA[rr*3+2], x2, fmaf(wA[rr*3+1], x1, fmaf(wA[rr*3+0], x0, acc[0][0][cx])));
                        acc[1][0][cx] = fmaf(wB[rr*3+2], x2, fmaf(wB[rr*3+1], x1, fmaf(wB[rr*3+0], x0, acc[1][0][cx])));
                    }
                    if (rr >= 1) {
                        acc[0][1][cx] = fmaf(wA[(rr-1)*3+2], x2, fmaf(wA[(rr-1)*3+1], x1, fmaf(wA[(rr-1)*3+0], x0, acc[0][1][cx])));
                        acc[1][1][cx] = fmaf(wB[(rr-1)*3+2], x2, fmaf(wB[(rr-1)*3+1], x1, fmaf(wB[(rr-1)*3+0], x0, acc[1][1][cx])));
                    }
                    x0 = x1; x1 = x2;
                }
            }
        }
    }
    const float bA = c2b[ocA], bB = c2b[ocB];
    #pragma unroll
    for (int px = 0; px < 15; ++px) {
        const float vA = fmaxf(fmaxf(acc[0][0][2*px], acc[0][0][2*px+1]),
                               fmaxf(acc[0][1][2*px], acc[0][1][2*px+1]));
        const float vB = fmaxf(fmaxf(acc[1][0][2*px], acc[1][0][2*px+1]),
                               fmaxf(acc[1][1][2*px], acc[1][1][2*px+1]));
        pool2[((size_t)img * P2C + ocA) * 240 + pr * 15 + px] = fmaxf(vA + bA, 0.f);
        pool2[((size_t)img * P2C + ocB) * 240 + pr * 15 + px] = fmaxf(vB + bB, 0.f);
    }
}

// ---------------- fc1 split-K GEMM: part[ks][img][oc] -----------------------
__global__ __launch_bounds__(256) void k_fc1(const float* __restrict__ pool2,
                                             const float* __restrict__ fc1w,
                                             float* __restrict__ part)
{
    __shared__ float As[64][33];
    __shared__ float Ws[64][33];
    const int mt = blockIdx.x >> 4;   // 13 M-tiles of 64 images
    const int ks = blockIdx.x & 15;   // 16 K-splits of 960
    const int t = threadIdx.x;
    const int io = t & 15, oo = t >> 4;
    float acc[4][4];
    #pragma unroll
    for (int i = 0; i < 4; ++i)
        #pragma unroll
        for (int j = 0; j < 4; ++j) acc[i][j] = 0.f;
    for (int kk = 0; kk < 960; kk += 32) {
        __syncthreads();
        #pragma unroll
        for (int j = 0; j < 8; ++j) {
            const int e = t + j * 256;
            const int rrow = e >> 5, col = e & 31;
            const int img = mt * 64 + rrow;
            As[rrow][col] = (img < NIMG) ? pool2[(size_t)img * FCIN + ks * 960 + kk + col] : 0.f;
            Ws[rrow][col] = fc1w[(size_t)rrow * FCIN + ks * 960 + kk + col];
        }
        __syncthreads();
        #pragma unroll
        for (int k = 0; k < 32; ++k) {
            float av[4], wv[4];
            #pragma unroll
            for (int i = 0; i < 4; ++i) av[i] = As[io * 4 + i][k];
            #pragma unroll
            for (int j = 0; j < 4; ++j) wv[j] = Ws[oo * 4 + j][k];
            #pragma unroll
            for (int i = 0; i < 4; ++i)
                #pragma unroll
                for (int j = 0; j < 4; ++j) acc[i][j] = fmaf(av[i], wv[j], acc[i][j]);
        }
    }
    #pragma unroll
    for (int i = 0; i < 4; ++i)
        #pragma unroll
        for (int j = 0; j < 4; ++j)
            part[((size_t)ks * 832 + mt * 64 + io * 4 + i) * 64 + oo * 4 + j] = acc[i][j];
}

__device__ __forceinline__ float wave_sum(float v) {
    #pragma unroll
    for (int o = 32; o > 0; o >>= 1) v += __shfl_xor(v, o, 64);
    return v;
}
__device__ __forceinline__ float wave_max(float v) {
    #pragma unroll
    for (int o = 32; o > 0; o >>= 1) v = fmaxf(v, __shfl_xor(v, o, 64));
    return v;
}

// ---------------- reduce fc1 partials + relu, binary head, fc2 --------------
__global__ __launch_bounds__(64) void k_post(const float* __restrict__ part,
                                             const float* __restrict__ fc1b,
                                             const float* __restrict__ fbw,
                                             const float* __restrict__ fbb,
                                             const float* __restrict__ fc2w,
                                             const float* __restrict__ fc2b,
                                             float* __restrict__ out,
                                             float* __restrict__ fc2o)
{
    const int img = blockIdx.x, t = threadIdx.x;
    float s = fc1b[t];
    for (int ks = 0; ks < 16; ++ks) s += part[((size_t)ks * 832 + img) * 64 + t];
    const float f = fmaxf(s, 0.f);
    __shared__ float fl[64];
    fl[t] = f;
    __syncthreads();
    const float bsum = wave_sum(f * fbw[t]);
    if (t == 0) out[800 + img] = 1.f / (1.f + expf(-(bsum + fbb[0])));
    #pragma unroll
    for (int jj = 0; jj < 2; ++jj) {
        const int j = t + jj * 64;
        float a = fc2b[j];
        #pragma unroll 8
        for (int k = 0; k < 64; ++k) a = fmaf(fl[k], fc2w[j * 64 + k], a);
        fc2o[(size_t)img * 128 + j] = a;
    }
}

// ---------------- fusion + softmax + 32-iter water-filling rebalance --------
__global__ __launch_bounds__(64) void k_final(const float* __restrict__ hlast,
                                              const float* __restrict__ fc2o,
                                              const float* __restrict__ gw,
                                              const float* __restrict__ gb,
                                              const float* __restrict__ fw,
                                              const float* __restrict__ fb,
                                              const float* __restrict__ finw,
                                              const float* __restrict__ finb,
                                              float* __restrict__ out)
{
    const int b = blockIdx.x, t = threadIdx.x;
    __shared__ float cf[128], nf[64], fu[64];
    #pragma unroll
    for (int jj = 0; jj < 2; ++jj) {
        const int j = t + jj * 64;
        float s = 0.f;
        for (int n = 0; n < NSTK; ++n) s += fc2o[(size_t)(b * NSTK + n) * 128 + j];
        cf[j] = s * (1.0f / 50.0f);
    }
    float s = 0.f;
    if (t < NSTK) {
        s = gb[t];
        for (int k = 0; k < HID; ++k) s = fmaf(hlast[b * HID + k], gw[t * HID + k], s);
    }
    nf[t] = (t < NSTK) ? s : 0.f;
    __syncthreads();
    float f = fb[t];
    for (int k = 0; k < NSTK; ++k) f = fmaf(nf[k], fw[t * 178 + k], f);
    for (int k = 0; k < 128; ++k) f = fmaf(cf[k], fw[t * 178 + 50 + k], f);
    fu[t] = fmaxf(f, 0.f);
    __syncthreads();
    float L = -3.4e38f;
    if (t < NSTK) {
        L = finb[t];
        for (int k = 0; k < 64; ++k) L = fmaf(fu[k], finw[t * 64 + k], L);
    }
    const float m = wave_max(L);
    const float e = (t < NSTK) ? expf(L - m) : 0.f;
    const float se = wave_sum(e);
    const float wv = e / se;
    float old = wv;
    float wc = fminf(fmaxf(wv, 0.f), 0.1f);
    for (int it = 0; it < 32; ++it) {
        const float leftover = wave_sum(old - wc);
        const bool mask = (wc != 0.1f);
        const float ssum = wave_sum(mask ? wc : 0.f);
        const float gift = (mask && ssum > 0.f) ? leftover * wc / ssum : 0.f;
        old = wc + gift;
        wc = fminf(fmaxf(old, 0.f), 0.1f);
    }
    if (t < NSTK) out[b * NSTK + t] = wc;
}

// ---------------------------------------------------------------------------
extern "C" void kernel_launch(void* const* d_in, const int* in_sizes, int n_in,
                              void* d_out, int out_size, void* d_ws, size_t ws_size,
                              hipStream_t stream)
{
    const float* x_num = (const float*)d_in[0];
    const float* x_img = (const float*)d_in[1];
    const float* c1w  = (const float*)d_in[2];
    const float* c1b  = (const float*)d_in[3];
    const float* c2w  = (const float*)d_in[4];
    const float* c2b  = (const float*)d_in[5];
    const float* fc1w = (const float*)d_in[6];
    const float* fc1b = (const float*)d_in[7];
    const float* fbw  = (const float*)d_in[8];
    const float* fbb  = (const float*)d_in[9];
    const float* fc2w = (const float*)d_in[10];
    const float* fc2b = (const float*)d_in[11];
    const float* wih  = (const float*)d_in[12];
    const float* whh  = (const float*)d_in[13];
    const float* bih  = (const float*)d_in[14];
    const float* bhh  = (const float*)d_in[15];
    const float* gw   = (const float*)d_in[16];
    const float* gb   = (const float*)d_in[17];
    const float* fw   = (const float*)d_in[18];
    const float* fb   = (const float*)d_in[19];
    const float* finw = (const float*)d_in[20];
    const float* finb = (const float*)d_in[21];
    float* out = (float*)d_out;
    float* ws  = (float*)d_ws;
    if (ws_size < (size_t)WS_FLOATS * 4) return;  // fail loudly (validation will catch)

    float* wihT   = ws + OFF_WIHT;
    ushort_t* whhf = (ushort_t*)(ws + OFF_WHHF);
    float* GI     = ws + OFF_GI;
    float* hlast  = ws + OFF_HLAST;
    float* pool2  = ws + OFF_POOL2;
    float* part   = ws + OFF_FC1P;
    float* fc2o   = ws + OFF_FC2O;

    (void)hipFuncSetAttribute(reinterpret_cast<const void*>(k_mega),
                              hipFuncAttributeMaxDynamicSharedMemorySize, SMEM_BYTES);

    k_prep <<<267, 256, 0, stream>>>(wih, whh, wihT, whhf);
    k_gi   <<<SEQ * NBATCH, 384, 0, stream>>>(x_num, wihT, bih, GI);
    k_mega <<<NIMG + 1, 512, SMEM_BYTES, stream>>>(x_img, c1w, c1b, c2w, c2b,
                                                   GI, whhf, bhh, pool2, hlast);
    k_fc1  <<<13 * 16, 256, 0, stream>>>(pool2, fc1w, part);
    k_post <<<NIMG, 64, 0, stream>>>(part, fc1b, fbw, fbb, fc2w, fc2b, out, fc2o);
    k_final<<<NBATCH, 64, 0, stream>>>(hlast, fc2o, gw, gb, fw, fb, finw, finb, out);
}

// Round 2
// 405.933 us; speedup vs baseline: 3.1349x; 3.1349x over previous
//
#include <hip/hip_runtime.h>
#include <hip/hip_bf16.h>

typedef unsigned short ushort_t;
typedef short short8_t __attribute__((ext_vector_type(8)));
typedef float f32x4 __attribute__((ext_vector_type(4)));
typedef float f32x16 __attribute__((ext_vector_type(16)));

#define NBATCH 16
#define SEQ    60
#define NSTK   50
#define HID    128
#define G3     384      // 3*HID
#define NIMG   800      // B*N images
#define IH     64
#define IW     60
#define P1H    32
#define P1W    30
#define P2C    64
#define FCIN   15360

// ---- workspace layout (float offsets) ----
#define OFF_WIHT   0u           // 50*384                = 19200
#define OFF_WHHF   19200u       // 49152 ushort          = 24576 floats (W_hh^T bf16, GRU MFMA frags)
#define OFF_WPREP  43776u       // 18432 ushort          = 9216 floats  (conv2 W bf16, MFMA A frags)
#define OFF_GI     52992u       // 60*16*384             = 368640
#define OFF_HLAST  421632u      // 16*128                = 2048
#define OFF_POOL2  423680u      // 800*15360 bf16        = 6144000 floats
#define OFF_FC1P   6567680u     // 16*832*64             = 851968
#define OFF_FC2O   7419648u     // 800*128               = 102400
#define WS_FLOATS  7522048u     // ~30 MB

// ---------------- shared-memory layouts for the mega kernel ----------------
struct __align__(16) ConvS {
    float    imgp[66][62];             // zero-padded input image       16368 B
    ushort_t pool1t[34][4][34][8];     // pool1 bf16, [y+1][ic>>3][x+1][ic&7]  73984 B
    ushort_t pool2s[64][240];          // pool2 bf16 staging            30720 B
    float    w1[288];
    float    b1[32];
};                                      // total 122352 B
struct GruS {
    float   h[2048];
    float   gh[6144];
    ushort_t hb[2048];
    ushort_t wf[49152];
};                                      // 135168 B
#define SMEM_BYTES 140544
#define ZWORDS ((16368 + 73984) / 4)    // imgp + pool1t zero-init words = 22588

// ---------------- prep: W_ih^T, W_hh GRU frags, conv2-W A frags ----------------
__global__ __launch_bounds__(256) void k_prep(const float* __restrict__ wih,
                                              const float* __restrict__ whh,
                                              const float* __restrict__ c2w,
                                              float* __restrict__ wihT,
                                              ushort_t* __restrict__ whhf,
                                              ushort_t* __restrict__ wprep)
{
    const int idx = blockIdx.x * 256 + threadIdx.x;
    if (idx < 19200) {
        const int j = idx % G3, k = idx / G3;
        wihT[idx] = wih[j * NSTK + k];
    } else if (idx < 19200 + 49152) {
        const int e = idx - 19200;
        // e = (((jt*4+ks)*64 + l)*8 + i)
        const int i = e & 7, l = (e >> 3) & 63, ksj = e >> 9;
        const int ks = ksj & 3, jt = ksj >> 2;
        const int j = jt * 16 + (l & 15);                 // B col = lane&15
        const int k = ks * 32 + ((l >> 4) << 3) + i;      // B k   = (lane>>4)*8+i
        __hip_bfloat16 hv = __float2bfloat16(whh[j * HID + k]);
        whhf[e] = *(ushort_t*)&hv;
    } else if (idx < 19200 + 49152 + 18432) {
        const int e = idx - 68352;
        // e = (((m*9+tap)*2+ks)*64 + l)*8 + i   -> A frag for mfma_32x32x16
        const int i = e & 7, l = (e >> 3) & 63, rest = e >> 9;
        const int ks = rest & 1, mt = rest >> 1;
        const int tap = mt % 9, mm = mt / 9;
        const int oc = mm * 32 + (l & 31);                // A row = lane&31
        const int ic = ks * 16 + ((l >> 5) << 3) + i;     // A k   = (lane>>5)*8+i
        __hip_bfloat16 hv = __float2bfloat16(c2w[((size_t)oc * 32 + ic) * 9 + tap]);
        wprep[e] = *(ushort_t*)&hv;
    }
}

// ---------------- GI[s][b][j] = b_ih[j] + x[b,s,:] . W_ih[j,:] ----------------
__global__ __launch_bounds__(384) void k_gi(const float* __restrict__ xnum,
                                            const float* __restrict__ wihT,
                                            const float* __restrict__ bih,
                                            float* __restrict__ GI)
{
    const int sb = blockIdx.x;
    const int s = sb >> 4, b = sb & 15;
    const int j = threadIdx.x;
    const float* xr = xnum + (size_t)(b * SEQ + s) * NSTK;
    float a = bih[j];
    for (int k = 0; k < NSTK; ++k) a = fmaf(xr[k], wihT[k * G3 + j], a);
    GI[((size_t)s * 16 + b) * G3 + j] = a;
}

// ---------------- mega kernel: block 0 = GRU, blocks 1..800 = one image each ----
__global__ __launch_bounds__(512, 2) void k_mega(const float* __restrict__ x_img,
                                                 const float* __restrict__ c1w,
                                                 const float* __restrict__ c1b,
                                                 const float* __restrict__ c2b,
                                                 const ushort_t* __restrict__ wprep,
                                                 const float* __restrict__ GI,
                                                 const ushort_t* __restrict__ whhf,
                                                 const float* __restrict__ bhh,
                                                 ushort_t* __restrict__ pool2,
                                                 float* __restrict__ hlast)
{
    extern __shared__ char smraw[];
    const int tid = threadIdx.x;
    const int bid = blockIdx.x;

    if (bid == 0) {
        // ================= GRU (bf16 MFMA for h @ W_hh^T) =================
        GruS* g = (GruS*)smraw;
        for (int i = tid; i < 24576; i += 512)
            ((unsigned int*)g->wf)[i] = ((const unsigned int*)whhf)[i];
        for (int i = tid; i < 2048; i += 512) { g->h[i] = 0.f; g->hb[i] = (ushort_t)0; }
        __syncthreads();
        const int w = tid >> 6, l = tid & 63;
        const int arow = l & 15, kq = l >> 4;
        for (int s = 0; s < SEQ; ++s) {
            #pragma unroll
            for (int jj = 0; jj < 3; ++jj) {
                const int jt = w * 3 + jj;
                f32x4 a = {0.f, 0.f, 0.f, 0.f};
                #pragma unroll
                for (int ks = 0; ks < 4; ++ks) {
                    short8_t af = *(const short8_t*)&g->hb[arow * 128 + ks * 32 + kq * 8];
                    short8_t bf = *(const short8_t*)&g->wf[(((jt << 2) | ks) * 64 + l) * 8];
                    a = __builtin_amdgcn_mfma_f32_16x16x32_bf16(af, bf, a, 0, 0, 0);
                }
                #pragma unroll
                for (int r = 0; r < 4; ++r)
                    g->gh[(kq * 4 + r) * G3 + jt * 16 + arow] = a[r];
            }
            __syncthreads();
            const float* gis = GI + (size_t)s * 16 * G3;
            #pragma unroll
            for (int q = 0; q < 4; ++q) {
                const int p = tid + q * 512;
                const int b = p >> 7, hh = p & 127;
                const float gir = gis[b * G3 + hh];
                const float giz = gis[b * G3 + 128 + hh];
                const float gin = gis[b * G3 + 256 + hh];
                const float ghr = g->gh[b * G3 + hh]       + bhh[hh];
                const float ghz = g->gh[b * G3 + 128 + hh] + bhh[128 + hh];
                const float ghn = g->gh[b * G3 + 256 + hh] + bhh[256 + hh];
                const float rg = 1.f / (1.f + expf(-(gir + ghr)));
                const float zg = 1.f / (1.f + expf(-(giz + ghz)));
                const float ng = tanhf(gin + rg * ghn);
                const float hn = (1.f - zg) * ng + zg * g->h[p];
                g->h[p] = hn;
                __hip_bfloat16 hb16 = __float2bfloat16(hn);
                g->hb[p] = *(ushort_t*)&hb16;
            }
            __syncthreads();
        }
        for (int i = tid; i < 2048; i += 512) hlast[i] = g->h[i];
        return;
    }

    // ======================= CNN branch, one image per block =======================
    ConvS* c = (ConvS*)smraw;
    const int img = bid - 1;
    const float* xim = x_img + (size_t)img * (IH * IW);

    for (int i = tid; i < ZWORDS; i += 512) ((unsigned int*)smraw)[i] = 0u;
    __syncthreads();
    for (int i = tid; i < IH * IW; i += 512) {
        const int y = i / IW, x = i - y * IW;
        c->imgp[y + 1][x + 1] = xim[i];
    }
    for (int i = tid; i < 288; i += 512) c->w1[i] = c1w[i];
    if (tid < 32) c->b1[tid] = c1b[tid];
    __syncthreads();

    // ---- conv1+relu+pool1: job = (cgroup, py, px); 8 channels, one b128 write ----
    #pragma unroll
    for (int jj = 0; jj < 8; ++jj) {
        const int j = tid + jj * 512;
        if (j < 3840) {
            const int px = j % 30;
            const int py = (j / 30) & 31;
            const int cg = j / 960;
            float patch[4][4];
            #pragma unroll
            for (int yy = 0; yy < 4; ++yy)
                #pragma unroll
                for (int xx = 0; xx < 4; ++xx)
                    patch[yy][xx] = c->imgp[2 * py + yy][2 * px + xx];
            short8_t outv;
            #pragma unroll
            for (int ch8 = 0; ch8 < 8; ++ch8) {
                const int ch = cg * 8 + ch8;
                float wr[9];
                #pragma unroll
                for (int q = 0; q < 9; ++q) wr[q] = c->w1[ch * 9 + q];
                const float bia = c->b1[ch];
                float best = 0.f;
                #pragma unroll
                for (int dy = 0; dy < 2; ++dy)
                    #pragma unroll
                    for (int dx = 0; dx < 2; ++dx) {
                        float sv = 0.f;
                        #pragma unroll
                        for (int ky = 0; ky < 3; ++ky)
                            #pragma unroll
                            for (int kx = 0; kx < 3; ++kx)
                                sv = fmaf(patch[dy + ky][dx + kx], wr[ky * 3 + kx], sv);
                        best = fmaxf(best, sv + bia);
                    }
                __hip_bfloat16 hv = __float2bfloat16(best);
                outv[ch8] = *(short*)&hv;
            }
            *(short8_t*)&c->pool1t[py + 1][cg][px + 1][0] = outv;
        }
    }
    __syncthreads();

    // ---- conv2 via bf16 MFMA 32x32x16 implicit GEMM + fused relu/pool2 ----
    {
        const int w  = tid >> 6, l = tid & 63;
        const int m  = w & 1;              // oc tile (32 oc)
        const int hi = l >> 5;             // half-wave -> k-chunk
        const int col = l & 31;            // output x position within tile

        short8_t af[9][2];
        #pragma unroll
        for (int tap = 0; tap < 9; ++tap)
            #pragma unroll
            for (int ks = 0; ks < 2; ++ks)
                af[tap][ks] = *(const short8_t*)&wprep[(((m * 9 + tap) * 2 + ks) * 64 + l) * 8];
        float bia[16];
        #pragma unroll
        for (int r = 0; r < 16; ++r)
            bia[r] = c2b[m * 32 + (r & 3) + 8 * (r >> 2) + 4 * hi];

        for (int yp = (w >> 1); yp < 16; yp += 4) {
            const int y0 = 2 * yp;
            f32x16 a0 = {0.f}; f32x16 a1 = {0.f};
            #pragma unroll
            for (int r = 0; r < 16; ++r) { a0[r] = 0.f; a1[r] = 0.f; }
            #pragma unroll
            for (int ro = 0; ro < 4; ++ro) {
                short8_t bf[3][2];
                #pragma unroll
                for (int kx = 0; kx < 3; ++kx)
                    #pragma unroll
                    for (int ks = 0; ks < 2; ++ks)
                        bf[kx][ks] = *(const short8_t*)&c->pool1t[y0 + ro][ks * 2 + hi][kx + col][0];
                if (ro < 3) {
                    #pragma unroll
                    for (int kx = 0; kx < 3; ++kx)
                        #pragma unroll
                        for (int ks = 0; ks < 2; ++ks)
                            a0 = __builtin_amdgcn_mfma_f32_32x32x16_bf16(af[ro * 3 + kx][ks], bf[kx][ks], a0, 0, 0, 0);
                }
                if (ro >= 1) {
                    #pragma unroll
                    for (int kx = 0; kx < 3; ++kx)
                        #pragma unroll
                        for (int ks = 0; ks < 2; ++ks)
                            a1 = __builtin_amdgcn_mfma_f32_32x32x16_bf16(af[(ro - 1) * 3 + kx][ks], bf[kx][ks], a1, 0, 0, 0);
                }
            }
            // pool 2x2 (y-pair elementwise, x-pair via shfl) + bias + relu
            #pragma unroll
            for (int r = 0; r < 16; ++r) {
                float v = fmaxf(a0[r], a1[r]);
                v = fmaxf(v, __shfl_xor(v, 1, 64));
                v = fmaxf(v + bia[r], 0.f);
                if ((col & 1) == 0 && col < 30) {
                    const int oc = m * 32 + (r & 3) + 8 * (r >> 2) + 4 * hi;
                    __hip_bfloat16 hv = __float2bfloat16(v);
                    c->pool2s[oc][yp * 15 + (col >> 1)] = *(ushort_t*)&hv;
                }
            }
        }
    }
    __syncthreads();

    // ---- coalesced flush of pool2 (bf16, fc1w k-order: oc*240 + py*15 + px) ----
    {
        int4* dst = (int4*)(pool2 + (size_t)img * FCIN);
        const int4* src = (const int4*)c->pool2s;
        #pragma unroll
        for (int jj = 0; jj < 4; ++jj) {
            const int i = tid + jj * 512;
            if (i < 1920) dst[i] = src[i];
        }
    }
}

// ---------------- fc1 split-K GEMM: part[ks][img][oc] -----------------------
__global__ __launch_bounds__(256) void k_fc1(const ushort_t* __restrict__ pool2,
                                             const float* __restrict__ fc1w,
                                             float* __restrict__ part)
{
    __shared__ float As[64][33];
    __shared__ float Ws[64][33];
    const int mt = blockIdx.x >> 4;
    const int ks = blockIdx.x & 15;
    const int t = threadIdx.x;
    const int io = t & 15, oo = t >> 4;
    float acc[4][4];
    #pragma unroll
    for (int i = 0; i < 4; ++i)
        #pragma unroll
        for (int j = 0; j < 4; ++j) acc[i][j] = 0.f;
    for (int kk = 0; kk < 960; kk += 32) {
        __syncthreads();
        #pragma unroll
        for (int j = 0; j < 8; ++j) {
            const int e = t + j * 256;
            const int rrow = e >> 5, col = e & 31;
            const int img = mt * 64 + rrow;
            float av = 0.f;
            if (img < NIMG) {
                ushort_t u = pool2[(size_t)img * FCIN + ks * 960 + kk + col];
                av = __bfloat162float(*(__hip_bfloat16*)&u);
            }
            As[rrow][col] = av;
            Ws[rrow][col] = fc1w[(size_t)rrow * FCIN + ks * 960 + kk + col];
        }
        __syncthreads();
        #pragma unroll
        for (int k = 0; k < 32; ++k) {
            float av[4], wv[4];
            #pragma unroll
            for (int i = 0; i < 4; ++i) av[i] = As[io * 4 + i][k];
            #pragma unroll
            for (int j = 0; j < 4; ++j) wv[j] = Ws[oo * 4 + j][k];
            #pragma unroll
            for (int i = 0; i < 4; ++i)
                #pragma unroll
                for (int j = 0; j < 4; ++j) acc[i][j] = fmaf(av[i], wv[j], acc[i][j]);
        }
    }
    #pragma unroll
    for (int i = 0; i < 4; ++i)
        #pragma unroll
        for (int j = 0; j < 4; ++j)
            part[((size_t)ks * 832 + mt * 64 + io * 4 + i) * 64 + oo * 4 + j] = acc[i][j];
}

__device__ __forceinline__ float wave_sum(float v) {
    #pragma unroll
    for (int o = 32; o > 0; o >>= 1) v += __shfl_xor(v, o, 64);
    return v;
}
__device__ __forceinline__ float wave_max(float v) {
    #pragma unroll
    for (int o = 32; o > 0; o >>= 1) v = fmaxf(v, __shfl_xor(v, o, 64));
    return v;
}

// ---------------- reduce fc1 partials + relu, binary head, fc2 --------------
__global__ __launch_bounds__(64) void k_post(const float* __restrict__ part,
                                             const float* __restrict__ fc1b,
                                             const float* __restrict__ fbw,
                                             const float* __restrict__ fbb,
                                             const float* __restrict__ fc2w,
                                             const float* __restrict__ fc2b,
                                             float* __restrict__ out,
                                             float* __restrict__ fc2o)
{
    const int img = blockIdx.x, t = threadIdx.x;
    float s = fc1b[t];
    for (int ks = 0; ks < 16; ++ks) s += part[((size_t)ks * 832 + img) * 64 + t];
    const float f = fmaxf(s, 0.f);
    __shared__ float fl[64];
    fl[t] = f;
    __syncthreads();
    const float bsum = wave_sum(f * fbw[t]);
    if (t == 0) out[800 + img] = 1.f / (1.f + expf(-(bsum + fbb[0])));
    #pragma unroll
    for (int jj = 0; jj < 2; ++jj) {
        const int j = t + jj * 64;
        float a = fc2b[j];
        #pragma unroll 8
        for (int k = 0; k < 64; ++k) a = fmaf(fl[k], fc2w[j * 64 + k], a);
        fc2o[(size_t)img * 128 + j] = a;
    }
}

// ---------------- fusion + softmax + 32-iter water-filling rebalance --------
__global__ __launch_bounds__(64) void k_final(const float* __restrict__ hlast,
                                              const float* __restrict__ fc2o,
                                              const float* __restrict__ gw,
                                              const float* __restrict__ gb,
                                              const float* __restrict__ fw,
                                              const float* __restrict__ fb,
                                              const float* __restrict__ finw,
                                              const float* __restrict__ finb,
                                              float* __restrict__ out)
{
    const int b = blockIdx.x, t = threadIdx.x;
    __shared__ float cf[128], nf[64], fu[64];
    #pragma unroll
    for (int jj = 0; jj < 2; ++jj) {
        const int j = t + jj * 64;
        float s = 0.f;
        for (int n = 0; n < NSTK; ++n) s += fc2o[(size_t)(b * NSTK + n) * 128 + j];
        cf[j] = s * (1.0f / 50.0f);
    }
    float s = 0.f;
    if (t < NSTK) {
        s = gb[t];
        for (int k = 0; k < HID; ++k) s = fmaf(hlast[b * HID + k], gw[t * HID + k], s);
    }
    nf[t] = (t < NSTK) ? s : 0.f;
    __syncthreads();
    float f = fb[t];
    for (int k = 0; k < NSTK; ++k) f = fmaf(nf[k], fw[t * 178 + k], f);
    for (int k = 0; k < 128; ++k) f = fmaf(cf[k], fw[t * 178 + 50 + k], f);
    fu[t] = fmaxf(f, 0.f);
    __syncthreads();
    float L = -3.4e38f;
    if (t < NSTK) {
        L = finb[t];
        for (int k = 0; k < 64; ++k) L = fmaf(fu[k], finw[t * 64 + k], L);
    }
    const float m = wave_max(L);
    const float e = (t < NSTK) ? expf(L - m) : 0.f;
    const float se = wave_sum(e);
    const float wv = e / se;
    float old = wv;
    float wc = fminf(fmaxf(wv, 0.f), 0.1f);
    for (int it = 0; it < 32; ++it) {
        const float leftover = wave_sum(old - wc);
        const bool mask = (wc != 0.1f);
        const float ssum = wave_sum(mask ? wc : 0.f);
        const float gift = (mask && ssum > 0.f) ? leftover * wc / ssum : 0.f;
        old = wc + gift;
        wc = fminf(fmaxf(old, 0.f), 0.1f);
    }
    if (t < NSTK) out[b * NSTK + t] = wc;
}

// ---------------------------------------------------------------------------
extern "C" void kernel_launch(void* const* d_in, const int* in_sizes, int n_in,
                              void* d_out, int out_size, void* d_ws, size_t ws_size,
                              hipStream_t stream)
{
    const float* x_num = (const float*)d_in[0];
    const float* x_img = (const float*)d_in[1];
    const float* c1w  = (const float*)d_in[2];
    const float* c1b  = (const float*)d_in[3];
    const float* c2w  = (const float*)d_in[4];
    const float* c2b  = (const float*)d_in[5];
    const float* fc1w = (const float*)d_in[6];
    const float* fc1b = (const float*)d_in[7];
    const float* fbw  = (const float*)d_in[8];
    const float* fbb  = (const float*)d_in[9];
    const float* fc2w = (const float*)d_in[10];
    const float* fc2b = (const float*)d_in[11];
    const float* wih  = (const float*)d_in[12];
    const float* whh  = (const float*)d_in[13];
    const float* bih  = (const float*)d_in[14];
    const float* bhh  = (const float*)d_in[15];
    const float* gw   = (const float*)d_in[16];
    const float* gb   = (const float*)d_in[17];
    const float* fw   = (const float*)d_in[18];
    const float* fb   = (const float*)d_in[19];
    const float* finw = (const float*)d_in[20];
    const float* finb = (const float*)d_in[21];
    float* out = (float*)d_out;
    float* ws  = (float*)d_ws;
    if (ws_size < (size_t)WS_FLOATS * 4) return;

    float* wihT     = ws + OFF_WIHT;
    ushort_t* whhf  = (ushort_t*)(ws + OFF_WHHF);
    ushort_t* wprep = (ushort_t*)(ws + OFF_WPREP);
    float* GI       = ws + OFF_GI;
    float* hlast    = ws + OFF_HLAST;
    ushort_t* pool2 = (ushort_t*)(ws + OFF_POOL2);
    float* part     = ws + OFF_FC1P;
    float* fc2o     = ws + OFF_FC2O;

    (void)hipFuncSetAttribute(reinterpret_cast<const void*>(k_mega),
                              hipFuncAttributeMaxDynamicSharedMemorySize, SMEM_BYTES);

    k_prep <<<339, 256, 0, stream>>>(wih, whh, c2w, wihT, whhf, wprep);
    k_gi   <<<SEQ * NBATCH, 384, 0, stream>>>(x_num, wihT, bih, GI);
    k_mega <<<NIMG + 1, 512, SMEM_BYTES, stream>>>(x_img, c1w, c1b, c2b, wprep,
                                                   GI, whhf, bhh, pool2, hlast);
    k_fc1  <<<13 * 16, 256, 0, stream>>>(pool2, fc1w, part);
    k_post <<<NIMG, 64, 0, stream>>>(part, fc1b, fbw, fbb, fc2w, fc2b, out, fc2o);
    k_final<<<NBATCH, 64, 0, stream>>>(hlast, fc2o, gw, gb, fw, fb, finw, finb, out);
}

// Round 3
// 145.045 us; speedup vs baseline: 8.7736x; 2.7987x over previous
//
#include <hip/hip_runtime.h>
#include <hip/hip_bf16.h>

typedef unsigned short ushort_t;
typedef short short8_t __attribute__((ext_vector_type(8)));
typedef float f32x4 __attribute__((ext_vector_type(4)));
typedef float f32x16 __attribute__((ext_vector_type(16)));
typedef ushort_t us4_t __attribute__((ext_vector_type(4)));

#define NBATCH 16
#define SEQ    60
#define NSTK   50
#define HID    128
#define G3     384      // 3*HID
#define NIMG   800      // B*N images
#define IH     64
#define IW     60
#define P1H    32
#define P1W    30
#define P2C    64
#define FCIN   15360

// ---- workspace layout (float offsets) ----
#define OFF_WIHT   0u          // 19200
#define OFF_WHHF   19200u      // 49152 ushort = 24576 f
#define OFF_WPREP  43776u      // 18432 ushort = 9216 f
#define OFF_FC2WT  52992u      // 8192 f
#define OFF_WFC1   61184u      // 983040 ushort = 491520 f
#define OFF_GI     552704u     // 368640
#define OFF_HLAST  921344u     // 2048
#define OFF_POOL2  923392u     // 832*15360 bf16 = 6389760 f (slack rows 800..831 for fc1 tiles)
#define OFF_FC1P   7313152u    // 16*832*64 = 851968
#define OFF_FC2O   8165120u    // 102400
#define WS_FLOATS  8267520u    // ~33 MB

// ---------------- shared-memory layouts for the mega kernel ----------------
struct __align__(16) ConvS {
    float    imgp[66][62];             // 16368 B
    ushort_t pool1t[34][4][34][8];     // 73984 B
    ushort_t pool2s[64][240];          // 30720 B
    float    w1[288];
    float    b1[32];
};                                      // 122352 B
struct __align__(16) GruS {
    float    gh[16 * 388];             // padded stride 388 -> 24832 B
    ushort_t hb[16 * 136];             // padded stride 136 ->  4352 B
};                                      // 29184 B
#define SMEM_BYTES 122368
#define ZWORDS ((16368 + 73984) / 4)

__device__ __forceinline__ float fast_sig(float x) {
    const float e = __expf(-x);
    return __builtin_amdgcn_rcpf(1.f + e);
}
__device__ __forceinline__ float fast_tanh(float x) {
    const float xc = fmaxf(fminf(x, 15.f), -15.f);
    const float e = __expf(2.f * xc);
    return (e - 1.f) * __builtin_amdgcn_rcpf(e + 1.f);
}

// ---------------- prep: all weight reshapes/conversions ----------------
__global__ __launch_bounds__(256) void k_prep(const float* __restrict__ wih,
                                              const float* __restrict__ whh,
                                              const float* __restrict__ c2w,
                                              const float* __restrict__ fc2w,
                                              const float* __restrict__ fc1w,
                                              float* __restrict__ wihT,
                                              ushort_t* __restrict__ whhf,
                                              ushort_t* __restrict__ wprep,
                                              float* __restrict__ fc2wT,
                                              ushort_t* __restrict__ wfc1)
{
    const int idx = blockIdx.x * 256 + threadIdx.x;
    if (idx < 19200) {
        const int j = idx % G3, k = idx / G3;
        wihT[idx] = wih[j * NSTK + k];
    } else if (idx < 68352) {
        const int e = idx - 19200;          // (((jt*4+ks)*64 + l)*8 + i)
        const int i = e & 7, l = (e >> 3) & 63, ksj = e >> 9;
        const int ks = ksj & 3, jt = ksj >> 2;
        const int j = jt * 16 + (l & 15);
        const int k = ks * 32 + ((l >> 4) << 3) + i;
        __hip_bfloat16 hv = __float2bfloat16(whh[j * HID + k]);
        whhf[e] = *(ushort_t*)&hv;
    } else if (idx < 86784) {
        const int e = idx - 68352;          // (((m*9+tap)*2+ks)*64 + l)*8 + i
        const int i = e & 7, l = (e >> 3) & 63, rest = e >> 9;
        const int ks = rest & 1, mt = rest >> 1;
        const int tap = mt % 9, mm = mt / 9;
        const int oc = mm * 32 + (l & 31);
        const int ic = ks * 16 + ((l >> 5) << 3) + i;
        __hip_bfloat16 hv = __float2bfloat16(c2w[((size_t)oc * 32 + ic) * 9 + tap]);
        wprep[e] = *(ushort_t*)&hv;
    } else if (idx < 94976) {
        const int e = idx - 86784;          // fc2wT[k*128 + j] = fc2w[j*64 + k]
        const int j = e & 127, k = e >> 7;
        fc2wT[e] = fc2w[j * 64 + k];
    } else if (idx < 1078016) {
        const int e = idx - 94976;          // ((T*4+n)*64 + l)*8 + i
        const int i = e & 7, l = (e >> 3) & 63, rest = e >> 9;
        const int n = rest & 3, T = rest >> 2;
        const int oc = n * 16 + (l & 15);
        const int k = T * 32 + ((l >> 4) << 3) + i;
        __hip_bfloat16 hv = __float2bfloat16(fc1w[(size_t)oc * FCIN + k]);
        wfc1[e] = *(ushort_t*)&hv;
    }
}

// ---------------- GI[s][b][j] = b_ih[j] + x[b,s,:] . W_ih[j,:] ----------------
__global__ __launch_bounds__(384) void k_gi(const float* __restrict__ xnum,
                                            const float* __restrict__ wihT,
                                            const float* __restrict__ bih,
                                            float* __restrict__ GI)
{
    const int sb = blockIdx.x;
    const int s = sb >> 4, b = sb & 15;
    const int j = threadIdx.x;
    const float* xr = xnum + (size_t)(b * SEQ + s) * NSTK;
    float a = bih[j];
    for (int k = 0; k < NSTK; ++k) a = fmaf(xr[k], wihT[k * G3 + j], a);
    GI[((size_t)s * 16 + b) * G3 + j] = a;
}

// ---------------- mega kernel: block 0 = GRU, blocks 1..800 = one image each ----
__global__ __launch_bounds__(512, 2) void k_mega(const float* __restrict__ x_img,
                                                 const float* __restrict__ c1w,
                                                 const float* __restrict__ c1b,
                                                 const float* __restrict__ c2b,
                                                 const ushort_t* __restrict__ wprep,
                                                 const float* __restrict__ GI,
                                                 const ushort_t* __restrict__ whhf,
                                                 const float* __restrict__ bhh,
                                                 ushort_t* __restrict__ pool2,
                                                 float* __restrict__ hlast)
{
    extern __shared__ char smraw[];
    const int tid = threadIdx.x;
    const int bid = blockIdx.x;

    if (bid == 0) {
        // =========== GRU: W_hh frags in regs, GI prefetch, h in regs ===========
        GruS* g = (GruS*)smraw;
        const int w = tid >> 6, l = tid & 63;
        const int arow = l & 15, kq = l >> 4;
        short8_t wfr[3][4];
        #pragma unroll
        for (int jj = 0; jj < 3; ++jj)
            #pragma unroll
            for (int ks = 0; ks < 4; ++ks)
                wfr[jj][ks] = *(const short8_t*)&whhf[((((w * 3 + jj) * 4 + ks) * 64 + l) * 8)];

        const int b = tid >> 5, hh0 = (tid & 31) * 4;
        const f32x4 bhr = *(const f32x4*)&bhh[hh0];
        const f32x4 bhz = *(const f32x4*)&bhh[128 + hh0];
        const f32x4 bhn = *(const f32x4*)&bhh[256 + hh0];
        float h0 = 0.f, h1 = 0.f, h2 = 0.f, h3 = 0.f;
        for (int i = tid; i < 1088; i += 512) ((unsigned int*)g->hb)[i] = 0u;
        const float* gi0 = GI + b * G3 + hh0;
        f32x4 cr = *(const f32x4*)(gi0);
        f32x4 cz = *(const f32x4*)(gi0 + 128);
        f32x4 cn = *(const f32x4*)(gi0 + 256);
        __syncthreads();

        for (int s = 0; s < SEQ; ++s) {
            // prefetch next step's GI (hidden under MFMA + barrier)
            const int sn = (s + 1 < SEQ) ? s + 1 : s;
            const float* gnx = GI + ((size_t)sn * 16 + b) * G3 + hh0;
            const f32x4 nr = *(const f32x4*)(gnx);
            const f32x4 nz = *(const f32x4*)(gnx + 128);
            const f32x4 nn = *(const f32x4*)(gnx + 256);

            // gh = h @ W_hh^T  (reads hb from previous step)
            #pragma unroll
            for (int jj = 0; jj < 3; ++jj) {
                f32x4 a = {0.f, 0.f, 0.f, 0.f};
                #pragma unroll
                for (int ks = 0; ks < 4; ++ks) {
                    short8_t af = *(const short8_t*)&g->hb[arow * 136 + ks * 32 + kq * 8];
                    a = __builtin_amdgcn_mfma_f32_16x16x32_bf16(af, wfr[jj][ks], a, 0, 0, 0);
                }
                const int jt = w * 3 + jj;
                #pragma unroll
                for (int r = 0; r < 4; ++r)
                    g->gh[(kq * 4 + r) * 388 + jt * 16 + arow] = a[r];
            }
            __syncthreads();

            // gates (each thread owns 4 consecutive hh of one batch row)
            const f32x4 gr = *(const f32x4*)&g->gh[b * 388 + hh0];
            const f32x4 gz = *(const f32x4*)&g->gh[b * 388 + 128 + hh0];
            const f32x4 gn = *(const f32x4*)&g->gh[b * 388 + 256 + hh0];
            float hv0, hv1, hv2, hv3;
            {
                const float r0 = fast_sig(cr[0] + gr[0] + bhr[0]);
                const float z0 = fast_sig(cz[0] + gz[0] + bhz[0]);
                const float n0 = fast_tanh(cn[0] + r0 * (gn[0] + bhn[0]));
                hv0 = (1.f - z0) * n0 + z0 * h0;
                const float r1 = fast_sig(cr[1] + gr[1] + bhr[1]);
                const float z1 = fast_sig(cz[1] + gz[1] + bhz[1]);
                const float n1 = fast_tanh(cn[1] + r1 * (gn[1] + bhn[1]));
                hv1 = (1.f - z1) * n1 + z1 * h1;
                const float r2 = fast_sig(cr[2] + gr[2] + bhr[2]);
                const float z2 = fast_sig(cz[2] + gz[2] + bhz[2]);
                const float n2 = fast_tanh(cn[2] + r2 * (gn[2] + bhn[2]));
                hv2 = (1.f - z2) * n2 + z2 * h2;
                const float r3 = fast_sig(cr[3] + gr[3] + bhr[3]);
                const float z3 = fast_sig(cz[3] + gz[3] + bhz[3]);
                const float n3 = fast_tanh(cn[3] + r3 * (gn[3] + bhn[3]));
                hv3 = (1.f - z3) * n3 + z3 * h3;
            }
            h0 = hv0; h1 = hv1; h2 = hv2; h3 = hv3;
            us4_t hp;
            { __hip_bfloat16 t0 = __float2bfloat16(h0); hp[0] = *(ushort_t*)&t0; }
            { __hip_bfloat16 t1 = __float2bfloat16(h1); hp[1] = *(ushort_t*)&t1; }
            { __hip_bfloat16 t2 = __float2bfloat16(h2); hp[2] = *(ushort_t*)&t2; }
            { __hip_bfloat16 t3 = __float2bfloat16(h3); hp[3] = *(ushort_t*)&t3; }
            *(us4_t*)&g->hb[b * 136 + hh0] = hp;
            cr = nr; cz = nz; cn = nn;
            __syncthreads();
        }
        f32x4 ho = {h0, h1, h2, h3};
        *(f32x4*)&hlast[b * HID + hh0] = ho;
        return;
    }

    // ======================= CNN branch, one image per block =======================
    ConvS* c = (ConvS*)smraw;
    const int img = bid - 1;
    const float* xim = x_img + (size_t)img * (IH * IW);

    for (int i = tid; i < ZWORDS; i += 512) ((unsigned int*)smraw)[i] = 0u;
    __syncthreads();
    for (int i = tid; i < IH * IW; i += 512) {
        const int y = i / IW, x = i - y * IW;
        c->imgp[y + 1][x + 1] = xim[i];
    }
    for (int i = tid; i < 288; i += 512) c->w1[i] = c1w[i];
    if (tid < 32) c->b1[tid] = c1b[tid];
    __syncthreads();

    // ---- conv1+relu+pool1 ----
    #pragma unroll
    for (int jj = 0; jj < 8; ++jj) {
        const int j = tid + jj * 512;
        if (j < 3840) {
            const int px = j % 30;
            const int py = (j / 30) & 31;
            const int cg = j / 960;
            float patch[4][4];
            #pragma unroll
            for (int yy = 0; yy < 4; ++yy)
                #pragma unroll
                for (int xx = 0; xx < 4; ++xx)
                    patch[yy][xx] = c->imgp[2 * py + yy][2 * px + xx];
            short8_t outv;
            #pragma unroll
            for (int ch8 = 0; ch8 < 8; ++ch8) {
                const int ch = cg * 8 + ch8;
                float wr[9];
                #pragma unroll
                for (int q = 0; q < 9; ++q) wr[q] = c->w1[ch * 9 + q];
                const float bia = c->b1[ch];
                float best = 0.f;
                #pragma unroll
                for (int dy = 0; dy < 2; ++dy)
                    #pragma unroll
                    for (int dx = 0; dx < 2; ++dx) {
                        float sv = 0.f;
                        #pragma unroll
                        for (int ky = 0; ky < 3; ++ky)
                            #pragma unroll
                            for (int kx = 0; kx < 3; ++kx)
                                sv = fmaf(patch[dy + ky][dx + kx], wr[ky * 3 + kx], sv);
                        best = fmaxf(best, sv + bia);
                    }
                __hip_bfloat16 hv = __float2bfloat16(best);
                outv[ch8] = *(short*)&hv;
            }
            *(short8_t*)&c->pool1t[py + 1][cg][px + 1][0] = outv;
        }
    }
    __syncthreads();

    // ---- conv2 via bf16 MFMA 32x32x16 implicit GEMM + fused relu/pool2 ----
    {
        const int w  = tid >> 6, l = tid & 63;
        const int m  = w & 1;
        const int hi = l >> 5;
        const int col = l & 31;

        short8_t af[9][2];
        #pragma unroll
        for (int tap = 0; tap < 9; ++tap)
            #pragma unroll
            for (int ks = 0; ks < 2; ++ks)
                af[tap][ks] = *(const short8_t*)&wprep[(((m * 9 + tap) * 2 + ks) * 64 + l) * 8];
        float bia[16];
        #pragma unroll
        for (int r = 0; r < 16; ++r)
            bia[r] = c2b[m * 32 + (r & 3) + 8 * (r >> 2) + 4 * hi];

        for (int yp = (w >> 1); yp < 16; yp += 4) {
            const int y0 = 2 * yp;
            f32x16 a0; f32x16 a1;
            #pragma unroll
            for (int r = 0; r < 16; ++r) { a0[r] = 0.f; a1[r] = 0.f; }
            #pragma unroll
            for (int ro = 0; ro < 4; ++ro) {
                short8_t bf[3][2];
                #pragma unroll
                for (int kx = 0; kx < 3; ++kx)
                    #pragma unroll
                    for (int ks = 0; ks < 2; ++ks)
                        bf[kx][ks] = *(const short8_t*)&c->pool1t[y0 + ro][ks * 2 + hi][kx + col][0];
                if (ro < 3) {
                    #pragma unroll
                    for (int kx = 0; kx < 3; ++kx)
                        #pragma unroll
                        for (int ks = 0; ks < 2; ++ks)
                            a0 = __builtin_amdgcn_mfma_f32_32x32x16_bf16(af[ro * 3 + kx][ks], bf[kx][ks], a0, 0, 0, 0);
                }
                if (ro >= 1) {
                    #pragma unroll
                    for (int kx = 0; kx < 3; ++kx)
                        #pragma unroll
                        for (int ks = 0; ks < 2; ++ks)
                            a1 = __builtin_amdgcn_mfma_f32_32x32x16_bf16(af[(ro - 1) * 3 + kx][ks], bf[kx][ks], a1, 0, 0, 0);
                }
            }
            #pragma unroll
            for (int r = 0; r < 16; ++r) {
                float v = fmaxf(a0[r], a1[r]);
                v = fmaxf(v, __shfl_xor(v, 1, 64));
                v = fmaxf(v + bia[r], 0.f);
                if ((col & 1) == 0 && col < 30) {
                    const int oc = m * 32 + (r & 3) + 8 * (r >> 2) + 4 * hi;
                    __hip_bfloat16 hv = __float2bfloat16(v);
                    c->pool2s[oc][yp * 15 + (col >> 1)] = *(ushort_t*)&hv;
                }
            }
        }
    }
    __syncthreads();

    {
        int4* dst = (int4*)(pool2 + (size_t)img * FCIN);
        const int4* src = (const int4*)c->pool2s;
        #pragma unroll
        for (int jj = 0; jj < 4; ++jj) {
            const int i = tid + jj * 512;
            if (i < 1920) dst[i] = src[i];
        }
    }
}

// ---------------- fc1 split-K via bf16 MFMA: part[ks][img][oc] ----------------
__global__ __launch_bounds__(256) void k_fc1(const ushort_t* __restrict__ pool2,
                                             const ushort_t* __restrict__ wfc1,
                                             float* __restrict__ part)
{
    const int mt = blockIdx.x >> 4;   // 0..12
    const int ks = blockIdx.x & 15;   // K-split of 960
    const int w = threadIdx.x >> 6, l = threadIdx.x & 63;
    const int arow = l & 15, kq = l >> 4;
    const ushort_t* Ab = pool2 + (size_t)(mt * 64 + w * 16 + arow) * FCIN + ks * 960 + kq * 8;
    const ushort_t* Bb = wfc1 + (size_t)(ks * 120) * 512 + l * 8;
    f32x4 acc0 = {0.f,0.f,0.f,0.f}, acc1 = {0.f,0.f,0.f,0.f};
    f32x4 acc2 = {0.f,0.f,0.f,0.f}, acc3 = {0.f,0.f,0.f,0.f};
    #pragma unroll 6
    for (int t = 0; t < 30; ++t) {
        const short8_t a  = *(const short8_t*)(Ab + t * 32);
        const short8_t b0 = *(const short8_t*)(Bb + (size_t)(t * 4 + 0) * 512);
        const short8_t b1 = *(const short8_t*)(Bb + (size_t)(t * 4 + 1) * 512);
        const short8_t b2 = *(const short8_t*)(Bb + (size_t)(t * 4 + 2) * 512);
        const short8_t b3 = *(const short8_t*)(Bb + (size_t)(t * 4 + 3) * 512);
        acc0 = __builtin_amdgcn_mfma_f32_16x16x32_bf16(a, b0, acc0, 0, 0, 0);
        acc1 = __builtin_amdgcn_mfma_f32_16x16x32_bf16(a, b1, acc1, 0, 0, 0);
        acc2 = __builtin_amdgcn_mfma_f32_16x16x32_bf16(a, b2, acc2, 0, 0, 0);
        acc3 = __builtin_amdgcn_mfma_f32_16x16x32_bf16(a, b3, acc3, 0, 0, 0);
    }
    const int img = mt * 64 + w * 16 + kq * 4;
    #pragma unroll
    for (int r = 0; r < 4; ++r) {
        float* dst = &part[((size_t)ks * 832 + img + r) * 64];
        dst[arow]      = acc0[r];
        dst[16 + arow] = acc1[r];
        dst[32 + arow] = acc2[r];
        dst[48 + arow] = acc3[r];
    }
}

__device__ __forceinline__ float wave_sum(float v) {
    #pragma unroll
    for (int o = 32; o > 0; o >>= 1) v += __shfl_xor(v, o, 64);
    return v;
}
__device__ __forceinline__ float wave_max(float v) {
    #pragma unroll
    for (int o = 32; o > 0; o >>= 1) v = fmaxf(v, __shfl_xor(v, o, 64));
    return v;
}

// ---------------- reduce fc1 partials + relu, binary head, fc2 --------------
__global__ __launch_bounds__(64) void k_post(const float* __restrict__ part,
                                             const float* __restrict__ fc1b,
                                             const float* __restrict__ fbw,
                                             const float* __restrict__ fbb,
                                             const float* __restrict__ fc2wT,
                                             const float* __restrict__ fc2b,
                                             float* __restrict__ out,
                                             float* __restrict__ fc2o)
{
    const int img = blockIdx.x, t = threadIdx.x;
    float s = fc1b[t];
    for (int ks = 0; ks < 16; ++ks) s += part[((size_t)ks * 832 + img) * 64 + t];
    const float f = fmaxf(s, 0.f);
    __shared__ float fl[64];
    fl[t] = f;
    __syncthreads();
    const float bsum = wave_sum(f * fbw[t]);
    if (t == 0) out[800 + img] = 1.f / (1.f + expf(-(bsum + fbb[0])));
    float a0 = fc2b[t], a1 = fc2b[t + 64];
    #pragma unroll 8
    for (int k = 0; k < 64; ++k) {
        const float fk = fl[k];
        a0 = fmaf(fk, fc2wT[k * 128 + t], a0);
        a1 = fmaf(fk, fc2wT[k * 128 + 64 + t], a1);
    }
    fc2o[(size_t)img * 128 + t] = a0;
    fc2o[(size_t)img * 128 + 64 + t] = a1;
}

// ---------------- fusion + softmax + 32-iter water-filling rebalance --------
__global__ __launch_bounds__(64) void k_final(const float* __restrict__ hlast,
                                              const float* __restrict__ fc2o,
                                              const float* __restrict__ gw,
                                              const float* __restrict__ gb,
                                              const float* __restrict__ fw,
                                              const float* __restrict__ fb,
                                              const float* __restrict__ finw,
                                              const float* __restrict__ finb,
                                              float* __restrict__ out)
{
    const int b = blockIdx.x, t = threadIdx.x;
    __shared__ float cf[128], nf[64], fu[64];
    #pragma unroll
    for (int jj = 0; jj < 2; ++jj) {
        const int j = t + jj * 64;
        float s = 0.f;
        for (int n = 0; n < NSTK; ++n) s += fc2o[(size_t)(b * NSTK + n) * 128 + j];
        cf[j] = s * (1.0f / 50.0f);
    }
    float s = 0.f;
    if (t < NSTK) {
        s = gb[t];
        for (int k = 0; k < HID; ++k) s = fmaf(hlast[b * HID + k], gw[t * HID + k], s);
    }
    nf[t] = (t < NSTK) ? s : 0.f;
    __syncthreads();
    float f = fb[t];
    for (int k = 0; k < NSTK; ++k) f = fmaf(nf[k], fw[t * 178 + k], f);
    for (int k = 0; k < 128; ++k) f = fmaf(cf[k], fw[t * 178 + 50 + k], f);
    fu[t] = fmaxf(f, 0.f);
    __syncthreads();
    float L = -3.4e38f;
    if (t < NSTK) {
        L = finb[t];
        for (int k = 0; k < 64; ++k) L = fmaf(fu[k], finw[t * 64 + k], L);
    }
    const float m = wave_max(L);
    const float e = (t < NSTK) ? expf(L - m) : 0.f;
    const float se = wave_sum(e);
    const float wv = e / se;
    float old = wv;
    float wc = fminf(fmaxf(wv, 0.f), 0.1f);
    for (int it = 0; it < 32; ++it) {
        const float leftover = wave_sum(old - wc);
        const bool mask = (wc != 0.1f);
        const float ssum = wave_sum(mask ? wc : 0.f);
        const float gift = (mask && ssum > 0.f) ? leftover * wc / ssum : 0.f;
        old = wc + gift;
        wc = fminf(fmaxf(old, 0.f), 0.1f);
    }
    if (t < NSTK) out[b * NSTK + t] = wc;
}

// ---------------------------------------------------------------------------
extern "C" void kernel_launch(void* const* d_in, const int* in_sizes, int n_in,
                              void* d_out, int out_size, void* d_ws, size_t ws_size,
                              hipStream_t stream)
{
    const float* x_num = (const float*)d_in[0];
    const float* x_img = (const float*)d_in[1];
    const float* c1w  = (const float*)d_in[2];
    const float* c1b  = (const float*)d_in[3];
    const float* c2w  = (const float*)d_in[4];
    const float* c2b  = (const float*)d_in[5];
    const float* fc1w = (const float*)d_in[6];
    const float* fc1b = (const float*)d_in[7];
    const float* fbw  = (const float*)d_in[8];
    const float* fbb  = (const float*)d_in[9];
    const float* fc2w = (const float*)d_in[10];
    const float* fc2b = (const float*)d_in[11];
    const float* wih  = (const float*)d_in[12];
    const float* whh  = (const float*)d_in[13];
    const float* bih  = (const float*)d_in[14];
    const float* bhh  = (const float*)d_in[15];
    const float* gw   = (const float*)d_in[16];
    const float* gb   = (const float*)d_in[17];
    const float* fw   = (const float*)d_in[18];
    const float* fb   = (const float*)d_in[19];
    const float* finw = (const float*)d_in[20];
    const float* finb = (const float*)d_in[21];
    float* out = (float*)d_out;
    float* ws  = (float*)d_ws;
    if (ws_size < (size_t)WS_FLOATS * 4) return;

    float* wihT     = ws + OFF_WIHT;
    ushort_t* whhf  = (ushort_t*)(ws + OFF_WHHF);
    ushort_t* wprep = (ushort_t*)(ws + OFF_WPREP);
    float* fc2wT    = ws + OFF_FC2WT;
    ushort_t* wfc1  = (ushort_t*)(ws + OFF_WFC1);
    float* GI       = ws + OFF_GI;
    float* hlast    = ws + OFF_HLAST;
    ushort_t* pool2 = (ushort_t*)(ws + OFF_POOL2);
    float* part     = ws + OFF_FC1P;
    float* fc2o     = ws + OFF_FC2O;

    (void)hipFuncSetAttribute(reinterpret_cast<const void*>(k_mega),
                              hipFuncAttributeMaxDynamicSharedMemorySize, SMEM_BYTES);

    k_prep <<<4211, 256, 0, stream>>>(wih, whh, c2w, fc2w, fc1w,
                                      wihT, whhf, wprep, fc2wT, wfc1);
    k_gi   <<<SEQ * NBATCH, 384, 0, stream>>>(x_num, wihT, bih, GI);
    k_mega <<<NIMG + 1, 512, SMEM_BYTES, stream>>>(x_img, c1w, c1b, c2b, wprep,
                                                   GI, whhf, bhh, pool2, hlast);
    k_fc1  <<<13 * 16, 256, 0, stream>>>(pool2, wfc1, part);
    k_post <<<NIMG, 64, 0, stream>>>(part, fc1b, fbw, fbb, fc2wT, fc2b, out, fc2o);
    k_final<<<NBATCH, 64, 0, stream>>>(hlast, fc2o, gw, gb, fw, fb, finw, finb, out);
}